// Round 9
// baseline (165.822 us; speedup 1.0000x reference)
//
#include <hip/hip_runtime.h>
#include <stdint.h>

// ---------------------------------------------------------------------------
// MixingLayer: b=16, m=64, f=128, k=64, L2=16, LMAX=4. ALL I/O IS FP32.
// SEG = [0,1,1,1,2,2,2,2,2,3,3,3,3,3,3,3]
//
// Round-16: R8 step body kept verbatim; block halved to 64m (256 thr,
// 4 waves) and grid doubled to (64,16) = 1024 blocks = 4 blocks/CU
// (R8 profiled: 0 bank conflicts, VGPR 60, but grid 512 = only 2
// resident blocks/CU -> 2 barrier groups -> latency-bound at 48% LDS-pipe
// util). 4 independent barrier groups per CU interleave the per-step
// latency chains. Uniform DMA roles (every wave: 2 B-chunks + own y):
// single PIPE_BAR(6) steady, 4 at t=29, 0 at t=30 (queue trace verified).
//   * y in REGISTERS from ybT (32B/thread/step, coalesced, 3-ahead dbuf).
//   * sA 64x32 XOR-slot swizzle; sB pre-swizzled in Wb2. LDS 32,768 B.
//   * Cpart [bm][sp][n] (g_id 0..63 unchanged); finish/convert untouched.
// Known harness fixed cost: 256MiB workspace re-poison fill (~43 us/iter).
//
// ws layout (bytes):
//   Wb2 bf16 [16fb][128fy][128n][32] @ 0        (16,777,216)
//   xb  bf16 [1024 m][128 f][16] @ 16777216     ( 4,194,304)
//   ybT bf16 [128 fy][1024 m][16] @ 20971520    ( 4,194,304)
//   Cpart f32 [1024 bm][64 sp][128 n] @ 25165824 (33,554,432)
//   wfT f32 [2][64 k][4 l][128f] @ 58720256     (   262,144)
// ---------------------------------------------------------------------------

#define AS1 __attribute__((address_space(1)))
#define AS3 __attribute__((address_space(3)))

typedef __bf16 bf16x8 __attribute__((ext_vector_type(8)));
typedef float f32x4 __attribute__((ext_vector_type(4)));

__device__ __forceinline__ uint16_t f2b(float f) {
  uint32_t u = __float_as_uint(f);
  u += 0x7fffu + ((u >> 16) & 1u);   // RNE
  return (uint16_t)(u >> 16);
}

#if __has_builtin(__builtin_amdgcn_fdot2_f32_bf16)
typedef __bf16 bf16x2 __attribute__((ext_vector_type(2)));
__device__ __forceinline__ float dot2b(uint32_t a, uint32_t b, float c) {
  union { uint32_t u; bf16x2 v; } ua, ub;
  ua.u = a; ub.u = b;
  return __builtin_amdgcn_fdot2_f32_bf16(ua.v, ub.v, c, false);
}
#else
__device__ __forceinline__ float dot2b(uint32_t a, uint32_t b, float c) {
  float a0 = __uint_as_float(a << 16), a1 = __uint_as_float(a & 0xffff0000u);
  float b0 = __uint_as_float(b << 16), b1 = __uint_as_float(b & 0xffff0000u);
  return c + a0 * b0 + a1 * b1;
}
#endif

// ---------------------------------------------------------------------------
// K0: Wb2 (blocked, swizzle-baked) + xb + ybT (transposed) + wfT.
// grid: [0,4096) Wb2 ; [4096,5120) xb ; [5120,6144) ybT ; [6144,6176) wfT.
// ---------------------------------------------------------------------------
__global__ __launch_bounds__(256) void convert_all(
    const float* __restrict__ wx0, const float* __restrict__ wy0,
    const float* __restrict__ x, const float* __restrict__ y,
    const float* __restrict__ wxf, const float* __restrict__ wyf,
    uint16_t* __restrict__ Wb2, uint16_t* __restrict__ xb,
    uint16_t* __restrict__ ybT, float* __restrict__ wfT) {
  int bid = blockIdx.x, tid = threadIdx.x;
  if (bid < 4096) {  // Wb2: 1,048,576 chunks of 8 halves
    int c = bid * 256 + tid;
    int fb = c >> 16;
    int rem = c & 65535;
    int fy = rem >> 9;
    int rem2 = rem & 511;
    int n = rem2 >> 2, pos = rem2 & 3;
    int slot = pos ^ ((n >> 1) & 3);   // bake the sB read swizzle
    int k = n & 63;
    const float* src = (n < 64 ? wx0 : wy0) +
        ((size_t)(k * 128 + fy) * 512 + fb * 32 + slot * 8);
    float4 v0 = *(const float4*)src;
    float4 v1 = *(const float4*)(src + 4);
    uint32_t o0 = (uint32_t)f2b(v0.x) | ((uint32_t)f2b(v0.y) << 16);
    uint32_t o1 = (uint32_t)f2b(v0.z) | ((uint32_t)f2b(v0.w) << 16);
    uint32_t o2 = (uint32_t)f2b(v1.x) | ((uint32_t)f2b(v1.y) << 16);
    uint32_t o3 = (uint32_t)f2b(v1.z) | ((uint32_t)f2b(v1.w) << 16);
    *(uint4*)(Wb2 + (size_t)c * 8) = make_uint4(o0, o1, o2, o3);
    return;
  }
  if (bid >= 6144) {  // wfT: 32 blocks x 256 thr x 8 elems = 65536
    int base = (bid - 6144) * 2048 + tid * 8;
#pragma unroll
    for (int ii = 0; ii < 8; ++ii) {
      int idx = base + ii;
      int side = idx >> 15, rem = idx & 32767;
      int k = rem >> 9, l = (rem >> 7) & 3, f = rem & 127;
      const float* src = side ? wyf : wxf;
      wfT[idx] = src[((size_t)l * 128 + f) * 64 + k];
    }
    return;
  }
  if (bid < 5120) {  // xb: straight bf16 convert, layout [m][f][16c]
    size_t i = ((size_t)(bid - 4096) * 256 + tid) * 8;
    const float* s = x + i;
    float4 v0 = *(const float4*)s;
    float4 v1 = *(const float4*)(s + 4);
    uint32_t o0 = (uint32_t)f2b(v0.x) | ((uint32_t)f2b(v0.y) << 16);
    uint32_t o1 = (uint32_t)f2b(v0.z) | ((uint32_t)f2b(v0.w) << 16);
    uint32_t o2 = (uint32_t)f2b(v1.x) | ((uint32_t)f2b(v1.y) << 16);
    uint32_t o3 = (uint32_t)f2b(v1.z) | ((uint32_t)f2b(v1.w) << 16);
    *(uint4*)(xb + i) = make_uint4(o0, o1, o2, o3);
    return;
  }
  {  // ybT[fy][m][16c] <- y[m][fy][16c]  (verified mapping, R3/R12)
    int c = (bid - 5120) * 256 + tid;      // unit = (m*128+fy)*2 + half
    int half = c & 1, fy = (c >> 1) & 127, m = c >> 8;
    const float* s = y + (size_t)c * 8;
    float4 v0 = *(const float4*)s;
    float4 v1 = *(const float4*)(s + 4);
    uint32_t o0 = (uint32_t)f2b(v0.x) | ((uint32_t)f2b(v0.y) << 16);
    uint32_t o1 = (uint32_t)f2b(v0.z) | ((uint32_t)f2b(v0.w) << 16);
    uint32_t o2 = (uint32_t)f2b(v1.x) | ((uint32_t)f2b(v1.y) << 16);
    uint32_t o3 = (uint32_t)f2b(v1.z) | ((uint32_t)f2b(v1.w) << 16);
    *(uint4*)(ybT + ((size_t)fy * 1024 + m) * 16 + half * 8) =
        make_uint4(o0, o1, o2, o3);
  }
}

// ---------------------------------------------------------------------------
// K1: FUSED G-gen + split GEMM, 4 waves / 64m-tile, y-in-registers,
// counted vmcnt. grid (64 groups, 16 M-tiles); group g: fb = g>>2,
// fyg = g&3 (32 fy). 32 steps, step t: fy = fyg*32 + t.  LDS 32,768 B.
// ---------------------------------------------------------------------------
__device__ __forceinline__ void gload_lds16(const void* g, void* l) {
  __builtin_amdgcn_global_load_lds((const AS1 uint32_t*)g, (AS3 uint32_t*)l, 16, 0, 0);
}

#define SB0 __builtin_amdgcn_sched_barrier(0)
#define PIPE_BAR(N) \
  asm volatile("s_waitcnt vmcnt(" #N ") lgkmcnt(0)\n\ts_barrier" ::: "memory")

__global__ __launch_bounds__(256, 4) void fused_gemm(
    const uint16_t* __restrict__ xb, const uint16_t* __restrict__ ybT,
    const uint16_t* __restrict__ Wb2, float* __restrict__ Cpart) {
  __shared__ __align__(16) uint16_t sA[2][64 * 32];   // XOR slot swizzle
  __shared__ __align__(16) uint16_t sB[3][128 * 32];  // swizzle baked in Wb2

  int tid = threadIdx.x;
  int w = tid >> 6, lane = tid & 63;
  int g_id = blockIdx.x;            // 0..63
  int fb = g_id >> 2, fyg = g_id & 3;
  int FB = fb * 8;
  int fy0 = fyg * 32;
  int m0 = blockIdx.y * 64;
  int r = lane & 15, q = lane >> 4;
  int wm = w >> 1, wn = w & 1;      // 2 x 2 wave grid over 64m x 128n
  int m_loc = tid & 63, quarter = tid >> 6;

  // ---- one-time: x[m, FB+quarter*2 .. +2, 0:16] packed into 16 dwords
  uint32_t xr[16];
  {
    const uint16_t* xp0 = xb + (size_t)(m0 + m_loc) * 2048 + (FB + quarter * 2) * 16;
#pragma unroll
    for (int j = 0; j < 4; ++j) {
      uint4 v = *(const uint4*)(xp0 + j * 8);
      xr[j * 4 + 0] = v.x; xr[j * 4 + 1] = v.y;
      xr[j * 4 + 2] = v.z; xr[j * 4 + 3] = v.w;
    }
  }

  f32x4 zero = {0.f, 0.f, 0.f, 0.f};
  f32x4 acc[2][4];
#pragma unroll
  for (int i = 0; i < 2; ++i)
#pragma unroll
    for (int j = 0; j < 4; ++j) acc[i][j] = zero;

  // ---- B DMA: every wave stages 2x1KB chunks per step (blk = w*2+jj).
  auto issueB = [&](uint16_t* dstB, int t) {
    size_t base = (size_t)(fb * 128 + fy0 + t) * 4096;  // halves
#pragma unroll
    for (int jj = 0; jj < 2; ++jj) {
      int blk = w * 2 + jj;  // wave-uniform
      gload_lds16(Wb2 + base + blk * 512 + lane * 8, dstB + blk * 512);
    }
  };

  // ---- y base: ybT[fy][m][16] -> per-thread coalesced 32B row reads.
  const uint16_t* ybase = ybT + (size_t)(m0 + m_loc) * 16;

  auto computeG = [&](uint4 ya, uint4 yc, float* gg) {
    uint32_t yp[8] = {ya.x, ya.y, ya.z, ya.w, yc.x, yc.y, yc.z, yc.w};
    uint32_t yl0 = yp[0] & 0xffffu, yh0 = yp[0] & 0xffff0000u;
    uint32_t yl4 = yp[4] & 0xffffu, yh4 = yp[4] & 0xffff0000u;
#pragma unroll
    for (int fxp = 0; fxp < 2; ++fxp) {
      const uint32_t* xp = xr + fxp * 8;
      gg[fxp * 4 + 0] = dot2b(xp[0], yl0, 0.f);
      gg[fxp * 4 + 1] = dot2b(xp[1], yp[1], dot2b(xp[0], yh0, 0.f));
      gg[fxp * 4 + 2] = dot2b(xp[4], yl4,
                         dot2b(xp[3], yp[3], dot2b(xp[2], yp[2], 0.f)));
      gg[fxp * 4 + 3] = dot2b(xp[7], yp[7], dot2b(xp[6], yp[6],
                         dot2b(xp[5], yp[5], dot2b(xp[4], yh4, 0.f))));
    }
  };
  auto writeA = [&](uint16_t* dstA, const float* gg) {
    uint32_t o[4];
#pragma unroll
    for (int p = 0; p < 4; ++p)
      o[p] = (__float_as_uint(gg[2 * p]) >> 16) |
             (__float_as_uint(gg[2 * p + 1]) & 0xffff0000u);
    int pos = quarter ^ ((m_loc >> 1) & 3);   // XOR slot swizzle
    *(uint4*)(dstA + m_loc * 32 + pos * 8) = make_uint4(o[0], o[1], o[2], o[3]);
  };

  uint16_t *pAc = sA[0], *pAn = sA[1];
  uint16_t *pBread = sB[0], *pBmid = sB[1], *pBissue = sB[2];

  float gg[8];
  // ---- prologue: B(0),B(1) DMAs first; y(0) temp; A(0); y(1),y(2) in regs.
  issueB(pBread, 0);
  issueB(pBmid, 1);
  SB0;
  uint4 yev0, yev1, yod0, yod1;
  {
    const uint16_t* yp0 = ybase + (size_t)fy0 * 16384;
    uint4 t0a = *(const uint4*)yp0;
    uint4 t0b = *(const uint4*)(yp0 + 8);
    computeG(t0a, t0b, gg);         // compiler wait drains B0,B1,y0
    writeA(pAc, gg);
    yev0 = *(const uint4*)(ybase + (size_t)(fy0 + 1) * 16384);
    yev1 = *(const uint4*)(ybase + (size_t)(fy0 + 1) * 16384 + 8);
    yod0 = *(const uint4*)(ybase + (size_t)(fy0 + 2) * 16384);
    yod1 = *(const uint4*)(ybase + (size_t)(fy0 + 2) * 16384 + 8);
  }
  SB0;
  PIPE_BAR(4);                       // keep y1,y2 in flight; B0/A0 visible

  // ---- step body. Step t: reads A(t)/B(t); computeG->A(t+1) from y(t+1)
  //      held in (y0_,y1_); reloads (y0_,y1_) <- y(t+3).
  auto body = [&](int t, uint4& y0_, uint4& y1_) {
    if (t <= 29) issueB(pBissue, t + 2);
    SB0;
    bf16x8 a[2], b[4];
#pragma unroll
    for (int i = 0; i < 2; ++i) {
      int row = wm * 32 + i * 16 + r;
      int pos = q ^ ((row >> 1) & 3);
      a[i] = *(const bf16x8*)&pAc[row * 32 + pos * 8];
    }
#pragma unroll
    for (int j = 0; j < 4; ++j) {
      int row = wn * 64 + j * 16 + r;
      int pos = q ^ ((row >> 1) & 3);
      b[j] = *(const bf16x8*)&pBread[row * 32 + pos * 8];
    }
    if (t < 31) {                    // produce A(t+1) from y(t+1) regs
      computeG(y0_, y1_, gg);
      writeA(pAn, gg);
    }
    if (t <= 28) {                   // reload y(t+3) (WAR after computeG)
      y0_ = *(const uint4*)(ybase + (size_t)(fy0 + t + 3) * 16384);
      y1_ = *(const uint4*)(ybase + (size_t)(fy0 + t + 3) * 16384 + 8);
    }
    SB0;
    __builtin_amdgcn_s_setprio(1);
#pragma unroll
    for (int i = 0; i < 2; ++i)
#pragma unroll
      for (int j = 0; j < 4; ++j)
        acc[i][j] = __builtin_amdgcn_mfma_f32_16x16x32_bf16(a[i], b[j], acc[i][j], 0, 0, 0);
    __builtin_amdgcn_s_setprio(0);

    // In-order queue trace (uniform, steady): at barrier the queue is
    // [B(t+1)^2, y(t+2)^2, B(t+2)^2, y(t+3)^2] = 8 -> vmcnt(6) retires
    // B(t+1) (issued one full step earlier). Tails: 29 -> 4, 30 -> 0.
    if (t <= 28)      PIPE_BAR(6);
    else if (t == 29) PIPE_BAR(4);
    else if (t == 30) PIPE_BAR(0);
    // t == 31: no barrier; straight to epilogue

    uint16_t* tp;
    tp = pAc; pAc = pAn; pAn = tp;
    tp = pBread; pBread = pBmid; pBmid = pBissue; pBissue = tp;
  };

  for (int t = 0; t < 32; t += 2) {
    body(t, yev0, yev1);             // even steps consume y(t+1) (odd idx)
    body(t + 1, yod0, yod1);         // odd steps consume y(t+1) (even idx)
  }

  // C/D layout: col(n)=lane&15, row(m)=(lane>>4)*4+reg
  // Cpart layout [bm][sp][n] (finish reads contiguous).
#pragma unroll
  for (int i = 0; i < 2; ++i)
#pragma unroll
    for (int j = 0; j < 4; ++j)
#pragma unroll
      for (int reg = 0; reg < 4; ++reg) {
        int mm = m0 + wm * 32 + i * 16 + q * 4 + reg;
        int nn = wn * 64 + j * 16 + r;
        Cpart[((size_t)mm * 64 + g_id) * 128 + nn] = acc[i][j][reg];
      }
}

// ---------------------------------------------------------------------------
// K2: ONE BLOCK PER bm: contiguous 32KB split-K reduce, MLP, gates, output.
// ---------------------------------------------------------------------------
__global__ __launch_bounds__(256) void finish_kernel(
    const float* __restrict__ x, const float* __restrict__ y,
    const float* __restrict__ wx_mlp, const float* __restrict__ bx_mlp,
    const float* __restrict__ wy_mlp, const float* __restrict__ by_mlp,
    const float* __restrict__ wfT,
    const float* __restrict__ Cpart, float* __restrict__ out) {
  const int seg[16] = {0,1,1,1,2,2,2,2,2,3,3,3,3,3,3,3};
  __shared__ float sred[256];
  __shared__ float sm[128];
  __shared__ float sg[2][128][4];
  int t = threadIdx.x;
  int bm = blockIdx.x;
  int mi = bm & 63;

  {  // split-K reduction: sm[n] = sum_{sp<64} Cpart[bm][sp][n] (contiguous)
    int col = t & 127, hh = t >> 7;
    const float* cp = Cpart + ((size_t)bm * 64 + hh * 32) * 128 + col;
    float s = 0.f;
#pragma unroll 8
    for (int sp = 0; sp < 32; ++sp)
      s += cp[(size_t)sp * 128];
    sred[t] = s;
  }
  __syncthreads();
  if (t < 128) sm[t] = sred[t] + sred[t + 128];  // [0:64)=mx, [64:128)=my
  __syncthreads();

  for (int st = 0; st < 2; ++st) {
    float v = 0.f;
    if (t < 128) {
      int side = t >> 6, j = t & 63;
      const float* wmlp = side ? wy_mlp : wx_mlp;
      const float* bmlp = side ? by_mlp : bx_mlp;
      const float* mv = sm + side * 64;
#pragma unroll 8
      for (int k = 0; k < 64; ++k)
        v += mv[k] * wmlp[(st * 64 + k) * 64 + j];
      v += bmlp[(st * 64 + mi) * 64 + j];
      v = v / (1.f + __expf(-v));
    }
    __syncthreads();
    if (t < 128) sm[t] = v;
    __syncthreads();
  }

  {  // gates: side wave-uniform, coalesced wfT reads
    int side = t >> 7, f = t & 127;
    const float* base = wfT + side * 32768;  // [k][l][f]
    const float* mv = sm + side * 64;
    float gg[4] = {0.f, 0.f, 0.f, 0.f};
#pragma unroll 8
    for (int k = 0; k < 64; ++k) {
      float m2 = mv[k];
#pragma unroll
      for (int l = 0; l < 4; ++l)
        gg[l] += m2 * base[(k * 4 + l) * 128 + f];
    }
#pragma unroll
    for (int l = 0; l < 4; ++l)
      sg[side][f][l] = gg[l] / (1.f + __expf(-gg[l]));
  }
  __syncthreads();

  {  // output: thread -> (f, half), 8 floats; fully coalesced
    int f = t >> 1, half = t & 1;
    size_t base = ((size_t)bm * 128 + f) * 16 + half * 8;
    float4 xa = *(const float4*)(x + base), xb4 = *(const float4*)(x + base + 4);
    float4 ya = *(const float4*)(y + base), yb4 = *(const float4*)(y + base + 4);
    float xv[8] = {xa.x, xa.y, xa.z, xa.w, xb4.x, xb4.y, xb4.z, xb4.w};
    float yv[8] = {ya.x, ya.y, ya.z, ya.w, yb4.x, yb4.y, yb4.z, yb4.w};
    float o[8];
#pragma unroll
    for (int ii = 0; ii < 8; ++ii) {
      int c = half * 8 + ii;
      o[ii] = sg[0][f][seg[c]] * xv[ii] + sg[1][f][seg[c]] * yv[ii];
    }
    *(float4*)(out + base)     = make_float4(o[0], o[1], o[2], o[3]);
    *(float4*)(out + base + 4) = make_float4(o[4], o[5], o[6], o[7]);
  }
}

// ---------------------------------------------------------------------------
extern "C" void kernel_launch(void* const* d_in, const int* in_sizes, int n_in,
                              void* d_out, int out_size, void* d_ws, size_t ws_size,
                              hipStream_t stream) {
  const float* x      = (const float*)d_in[0];
  const float* y      = (const float*)d_in[1];
  const float* wx0    = (const float*)d_in[2];
  const float* wy0    = (const float*)d_in[3];
  const float* wx_mlp = (const float*)d_in[4];
  const float* bx_mlp = (const float*)d_in[5];
  const float* wy_mlp = (const float*)d_in[6];
  const float* by_mlp = (const float*)d_in[7];
  const float* wxf    = (const float*)d_in[8];
  const float* wyf    = (const float*)d_in[9];
  float* out = (float*)d_out;

  uint16_t* Wb2   = (uint16_t*)d_ws;                               // 16,777,216 B
  uint16_t* xb    = (uint16_t*)((char*)d_ws + (size_t)16777216);   //  4,194,304 B
  uint16_t* ybT   = (uint16_t*)((char*)d_ws + (size_t)20971520);   //  4,194,304 B
  float*    Cpart = (float*)((char*)d_ws + (size_t)25165824);      // 33,554,432 B
  float*    wfT   = (float*)((char*)d_ws + (size_t)58720256);      //    262,144 B

  convert_all<<<6176, 256, 0, stream>>>(wx0, wy0, x, y, wxf, wyf, Wb2, xb, ybT, wfT);
  fused_gemm<<<dim3(64, 16), 256, 0, stream>>>(xb, ybT, Wb2, Cpart);
  finish_kernel<<<1024, 256, 0, stream>>>(x, y, wx_mlp, bx_mlp, wy_mlp, by_mlp,
                                          wfT, Cpart, out);
}